// Round 19
// baseline (66.332 us; speedup 1.0000x reference)
//
#include <hip/hip_runtime.h>
#include <cstdint>

#define MARGIN_F 0.2f

typedef __attribute__((ext_vector_type(4))) float fv4;   // MFMA accumulator
typedef __attribute__((ext_vector_type(2))) long lv2;    // 16B = 2 x i64 (fp8 frag pair)

// ---- async global->LDS, 16B per lane (dest = wave-uniform base + lane*16) ----
__device__ __forceinline__ void gload16(const void* g, void* l) {
    __builtin_amdgcn_global_load_lds(
        (const __attribute__((address_space(1))) unsigned*)g,
        (__attribute__((address_space(3))) unsigned*)l,
        16, 0, 0);
}

// =====================================================================
// prep: norms, d_pos (fp32 exact) + fp8 e4m3fn conversion of e1,e2.
// fp8 written in PERMUTED order within each 128B K-window so the main
// kernel reads one b128 per lane per MFMA-pair (zero-conflict pattern):
// source 8B block b (kk=b>>2, l4=b&3) -> tb = ((b>>3)<<3)|((b&3)<<1)|((b>>2)&1).
// grid: 4096 blocks x 128 threads
// =====================================================================
__global__ __launch_bounds__(128) void prep_kernel(
    const float* __restrict__ e1, const float* __restrict__ e2,
    unsigned* __restrict__ e1q, unsigned* __restrict__ e2q,   // 4 fp8 / uint
    float* __restrict__ n1, float* __restrict__ n2, float* __restrict__ dpos)
{
    const int row = blockIdx.x;
    const int t = threadIdx.x;
    const float4 a = reinterpret_cast<const float4*>(e1 + (size_t)row * 512)[t];
    const float4 b = reinterpret_cast<const float4*>(e2 + (size_t)row * 512)[t];

    int pa = __builtin_amdgcn_cvt_pk_fp8_f32(a.x, a.y, 0, false);
    pa     = __builtin_amdgcn_cvt_pk_fp8_f32(a.z, a.w, pa, true);
    int pb = __builtin_amdgcn_cvt_pk_fp8_f32(b.x, b.y, 0, false);
    pb     = __builtin_amdgcn_cvt_pk_fp8_f32(b.z, b.w, pb, true);

    const int wq    = t >> 5;          // 128B window 0..3
    const int u     = t & 31;          // uint slot in window
    const int blk   = u >> 1;          // 8B block 0..15
    const int piece = u & 1;
    const int tb    = ((blk >> 3) << 3) | ((blk & 3) << 1) | ((blk >> 2) & 1);
    const int di    = (wq << 5) + (tb << 1) + piece;
    e1q[row * 128 + di] = (unsigned)pa;
    e2q[row * 128 + di] = (unsigned)pb;

    float s1 = a.x*a.x + a.y*a.y + a.z*a.z + a.w*a.w;
    float s2 = b.x*b.x + b.y*b.y + b.z*b.z + b.w*b.w;
    float dx = a.x-b.x, dy = a.y-b.y, dz = a.z-b.z, dw = a.w-b.w;
    float sp = dx*dx + dy*dy + dz*dz + dw*dw;

    #pragma unroll
    for (int o = 32; o; o >>= 1) {
        s1 += __shfl_down(s1, o);
        s2 += __shfl_down(s2, o);
        sp += __shfl_down(sp, o);
    }
    __shared__ float r1[2], r2[2], rp[2];
    if ((t & 63) == 0) { int wv = t >> 6; r1[wv] = s1; r2[wv] = s2; rp[wv] = sp; }
    __syncthreads();
    if (t == 0) {
        n1[row] = r1[0] + r1[1];
        n2[row] = r2[0] + r2[1];
        dpos[row] = sqrtf(rp[0] + rp[1]);
    }
}

// ---- flat tile decode: tau in [0,2080) -> (flavor, bi, bj) ----
__device__ __forceinline__ void decode_tile(int tau, int& fl, int& bi, int& bj) {
    if (tau < 1024) { fl = 0; bi = tau >> 5; bj = tau & 31; }
    else {
        int b = tau - 1024; fl = 1;
        if (b >= 528) { b -= 528; fl = 2; }
        int r = 0;
        while (b >= 32 - r) { b -= 32 - r; ++r; }
        bi = r; bj = r + b;
    }
}

// =====================================================================
// main: R17 body on a 4-BLOCKS/CU one-round grid: 1024 blocks (exactly
// 4/CU, all resident at t=0, 4 independent barrier domains per CU so
// one block's stage->barrier drain overlaps other blocks' MFMA/VALU).
// Per tile: 4 K-steps BK=128 (stage -> sync -> 64 MFMA -> sync), next
// tile's step-0 stage issues before the epilogue.
// grid: 1024 blocks x 256 threads; flat tile list 992x2 + 32x3 tiles.
// =====================================================================
__global__ __launch_bounds__(256, 4) void triplet_main(
    const unsigned char* __restrict__ e1q, const unsigned char* __restrict__ e2q,
    const float* __restrict__ n1, const float* __restrict__ n2,
    const float* __restrict__ dpos,
    float* __restrict__ total, unsigned* __restrict__ count)
{
    __shared__ char buf[32768];        // A tile [0,16K) | B tile [16K,32K)
    __shared__ float scRN[128], scRD[128], scCN[128], scCD[128];
    __shared__ float lt[4];
    __shared__ unsigned lc[4];

    const int g    = blockIdx.x;
    int       tau  = (2080 * g) >> 10;         // /1024
    const int tend = (2080 * (g + 1)) >> 10;

    const int tid  = threadIdx.x;
    const int w    = tid >> 6;
    const int lane = tid & 63;
    const int l15  = lane & 15;
    const int l4   = lane >> 4;
    const int wr   = w >> 1;      // 0..1
    const int wc   = w & 1;       // 0..1

    // ---- i-relative staging offsets (fp8 row = 512B; window = 128B) ----
    long srcRel[4];
    #pragma unroll
    for (int c = 0; c < 4; ++c) {
        const int chA = tid + (c << 8);              // 0..1023
        const int rA  = chA >> 3;                    // 0..127
        srcRel[c] = (long)rA * 512 + (((chA & 7) << 4) ^ ((rA & 7) << 4));
    }
    const int ldst = w << 10;                        // wave-uniform dest part

#define STAGE(T, XB, YB) do {                                                \
    const long kb_ = (long)(T) << 7;                                         \
    _Pragma("unroll")                                                        \
    for (int c = 0; c < 4; ++c) {                                            \
        gload16((XB) + srcRel[c] + kb_, buf + (c << 12) + ldst);             \
        gload16((YB) + srcRel[c] + kb_, buf + 16384 + (c << 12) + ldst);     \
    }                                                                        \
} while (0)

    // ---- zero-conflict swizzled b128 read bases; khalf = ^64 ----
    const int slot = (l4 << 4) ^ ((l15 & 7) << 4);
    const int aB = ((wr << 6) + l15) * 128 + slot;
    const int bB = 16384 + ((wc << 6) + l15) * 128 + slot;

    fv4 acc[4][4];

#define EPI(EMITCOL, NEEDNEQ) do {                                           \
    float cN_[4], cM_[4];                                                    \
    _Pragma("unroll")                                                        \
    for (int n = 0; n < 4; ++n) {                                            \
        const int cl = (wc << 6) + (n << 4) + l15;                           \
        cN_[n] = scCN[cl]; cM_[n] = scCD[cl] + MARGIN_F;                     \
    }                                                                        \
    _Pragma("unroll")                                                        \
    for (int m = 0; m < 4; ++m) {                                            \
        _Pragma("unroll")                                                    \
        for (int rr = 0; rr < 4; ++rr) {                                     \
            const int rl = (wr << 6) + (m << 4) + (l4 << 2) + rr;            \
            const float rN = scRN[rl];                                       \
            const float rM = scRD[rl] + MARGIN_F;                            \
            _Pragma("unroll")                                                \
            for (int n = 0; n < 4; ++n) {                                    \
                const float D = fmaxf(fmaf(-2.0f, acc[m][n][rr],             \
                                           rN + cN_[n]), 0.0f);              \
                const float s = __builtin_amdgcn_sqrtf(D);                   \
                bool neq = true;                                             \
                if (NEEDNEQ) neq = (rl != ((wc << 6) + (n << 4) + l15));     \
                const float t1 = rM - s;                                     \
                const bool c1 = (t1 < MARGIN_F) && neq;                      \
                lcnt += c1;                                                  \
                ltot += c1 ? fmaxf(t1, 0.0f) : 0.0f;                         \
                if (EMITCOL) {                                               \
                    const float t2 = cM_[n] - s;                             \
                    const bool c2 = (t2 < MARGIN_F) && neq;                  \
                    lcnt += c2;                                              \
                    ltot += c2 ? fmaxf(t2, 0.0f) : 0.0f;                     \
                }                                                            \
            }                                                                \
        }                                                                    \
    }                                                                        \
} while (0)

    // ---- decode + pointers for the first tile ----
    int fl, bi, bj;
    decode_tile(tau, fl, bi, bj);
    int i0 = bi << 7, j0 = bj << 7;
    const char* XB = (const char*)((fl == 2) ? e2q : e1q) + (long)i0 * 512;
    const char* YB = (const char*)((fl == 1) ? e1q : e2q) + (long)j0 * 512;
    const float* nRp = (fl == 2) ? n2 : n1;
    const float* nCp = (fl == 1) ? n1 : n2;

    // ---- prologue: scalars + first stage ----
    if (tid < 128)      { scRN[tid] = nRp[i0 + tid]; scRD[tid] = dpos[i0 + tid]; }
    else { const int t2 = tid - 128; scCN[t2] = nCp[j0 + t2]; scCD[t2] = dpos[j0 + t2]; }
    STAGE(0, XB, YB);

    float    ltot = 0.0f;
    unsigned lcnt = 0;

    for (;;) {
        const bool hasNext = (tau + 1 < tend);
        int nfl = 0, nbi = 0, nbj = 0, ni0 = 0, nj0 = 0;
        const char *nXB = XB, *nYB = YB;
        const float *nnR = nRp, *nnC = nCp;
        if (hasNext) {
            decode_tile(tau + 1, nfl, nbi, nbj);
            ni0 = nbi << 7; nj0 = nbj << 7;
            nXB = (const char*)((nfl == 2) ? e2q : e1q) + (long)ni0 * 512;
            nYB = (const char*)((nfl == 1) ? e1q : e2q) + (long)nj0 * 512;
            nnR = (nfl == 2) ? n2 : n1;
            nnC = (nfl == 1) ? n1 : n2;
        }

        #pragma unroll
        for (int m = 0; m < 4; ++m)
            #pragma unroll
            for (int n = 0; n < 4; ++n) acc[m][n] = (fv4)0.0f;

        // ---- K-loop: sync(stage landed) -> compute -> sync -> stage next --
        for (int t = 0; t < 4; ++t) {
            __syncthreads();
            #pragma unroll
            for (int h = 0; h < 2; ++h) {
                const int H = h << 6;
                lv2 a_[4], b_[4];
                #pragma unroll
                for (int m = 0; m < 4; ++m)
                    a_[m] = *(const lv2*)(buf + ((aB + m * 2048) ^ H));
                #pragma unroll
                for (int n = 0; n < 4; ++n)
                    b_[n] = *(const lv2*)(buf + ((bB + n * 2048) ^ H));
                #pragma unroll
                for (int m = 0; m < 4; ++m)
                    #pragma unroll
                    for (int n = 0; n < 4; ++n) {
                        acc[m][n] = __builtin_amdgcn_mfma_f32_16x16x32_fp8_fp8(
                            a_[m][0], b_[n][0], acc[m][n], 0, 0, 0);
                        acc[m][n] = __builtin_amdgcn_mfma_f32_16x16x32_fp8_fp8(
                            a_[m][1], b_[n][1], acc[m][n], 0, 0, 0);
                    }
            }
            __syncthreads();
            if (t < 3)      STAGE(t + 1, XB, YB);
            else if (hasNext) STAGE(0, nXB, nYB);   // hides under epilogue
        }

        // ---- lean specialized epilogue for this tile ----
        if (i0 != j0)      EPI(true, false);   // hot path
        else if (fl == 0)  EPI(true, true);    // G12 diag tiles
        else               EPI(false, true);   // G11/G22 diag tiles

        if (!hasNext) break;

        // ---- swap in next tile's scalars (behind barrier) ----
        __syncthreads();                 // epilogue scalar reads complete
        if (tid < 128)      { scRN[tid] = nnR[ni0 + tid]; scRD[tid] = dpos[ni0 + tid]; }
        else { const int t2 = tid - 128; scCN[t2] = nnC[nj0 + t2]; scCD[t2] = dpos[nj0 + t2]; }
        // next K-loop's first __syncthreads publishes these writes
        fl = nfl; i0 = ni0; j0 = nj0; XB = nXB; YB = nYB; nRp = nnR; nCp = nnC;
        ++tau;
    }
#undef STAGE
#undef EPI

    // ---- block reduction: wave shuffle -> LDS -> one atomic pair ----
    #pragma unroll
    for (int o = 32; o; o >>= 1) {
        ltot += __shfl_down(ltot, o);
        lcnt += __shfl_down(lcnt, o);
    }
    __syncthreads();
    if (lane == 0) { lt[w] = ltot; lc[w] = lcnt; }
    __syncthreads();
    if (tid == 0) {
        float T = 0.0f; unsigned C = 0;
        #pragma unroll
        for (int x = 0; x < 4; ++x) { T += lt[x]; C += lc[x]; }
        atomicAdd(total, T);
        atomicAdd(count, C);
    }
}

__global__ void finalize_kernel(const float* __restrict__ total,
                                const unsigned* __restrict__ count,
                                float* __restrict__ out)
{
    out[0] = total[0] / fmaxf((float)count[0], 1.0f);
}

// =====================================================================
// Workspace layout (~4.5 MB):
//   [0,8)        : total (f32), count (u32)
//   [1024, ...)  : n1[4096], n2[4096], dpos[4096]  (f32)
//   [131072, ..) : e1q 4096x512 fp8 (2MB), then e2q (2MB)
// =====================================================================
extern "C" void kernel_launch(void* const* d_in, const int* in_sizes, int n_in,
                              void* d_out, int out_size, void* d_ws, size_t ws_size,
                              hipStream_t stream) {
    const float* e1 = (const float*)d_in[0];
    const float* e2 = (const float*)d_in[1];
    char* ws = (char*)d_ws;

    float*    total = (float*)ws;
    unsigned* count = (unsigned*)(ws + 4);
    float* n1   = (float*)(ws + 1024);
    float* n2   = n1 + 4096;
    float* dpos = n2 + 4096;
    unsigned* e1q = (unsigned*)(ws + (1 << 17));
    unsigned* e2q = e1q + (size_t)4096 * 128;

    hipMemsetAsync(ws, 0, 64, stream);
    prep_kernel<<<4096, 128, 0, stream>>>(e1, e2, e1q, e2q, n1, n2, dpos);
    triplet_main<<<1024, 256, 0, stream>>>((const unsigned char*)e1q,
                                           (const unsigned char*)e2q,
                                           n1, n2, dpos, total, count);
    finalize_kernel<<<1, 1, 0, stream>>>(total, count, (float*)d_out);
}

// Round 20
// 56.684 us; speedup vs baseline: 1.1702x; 1.1702x over previous
//
#include <hip/hip_runtime.h>
#include <cstdint>

#define MARGIN_F 0.2f

typedef __attribute__((ext_vector_type(4))) float fv4;   // MFMA accumulator
typedef __attribute__((ext_vector_type(2))) long lv2;    // 16B = 2 x i64 (fp8 frag pair)

// ---- async global->LDS, 16B per lane (dest = wave-uniform base + lane*16) ----
__device__ __forceinline__ void gload16(const void* g, void* l) {
    __builtin_amdgcn_global_load_lds(
        (const __attribute__((address_space(1))) unsigned*)g,
        (__attribute__((address_space(3))) unsigned*)l,
        16, 0, 0);
}

// =====================================================================
// prep: norms, d_pos (fp32 exact) + fp8 e4m3fn conversion of e1,e2.
// fp8 written in PERMUTED order within each 128B K-window so the main
// kernel reads one b128 per lane per MFMA-pair (zero-conflict pattern):
// source 8B block b (kk=b>>2, l4=b&3) -> tb = ((b>>3)<<3)|((b&3)<<1)|((b>>2)&1).
// grid: 4096 blocks x 128 threads
// =====================================================================
__global__ __launch_bounds__(128) void prep_kernel(
    const float* __restrict__ e1, const float* __restrict__ e2,
    unsigned* __restrict__ e1q, unsigned* __restrict__ e2q,   // 4 fp8 / uint
    float* __restrict__ n1, float* __restrict__ n2, float* __restrict__ dpos)
{
    const int row = blockIdx.x;
    const int t = threadIdx.x;
    const float4 a = reinterpret_cast<const float4*>(e1 + (size_t)row * 512)[t];
    const float4 b = reinterpret_cast<const float4*>(e2 + (size_t)row * 512)[t];

    int pa = __builtin_amdgcn_cvt_pk_fp8_f32(a.x, a.y, 0, false);
    pa     = __builtin_amdgcn_cvt_pk_fp8_f32(a.z, a.w, pa, true);
    int pb = __builtin_amdgcn_cvt_pk_fp8_f32(b.x, b.y, 0, false);
    pb     = __builtin_amdgcn_cvt_pk_fp8_f32(b.z, b.w, pb, true);

    const int wq    = t >> 5;          // 128B window 0..3
    const int u     = t & 31;          // uint slot in window
    const int blk   = u >> 1;          // 8B block 0..15
    const int piece = u & 1;
    const int tb    = ((blk >> 3) << 3) | ((blk & 3) << 1) | ((blk >> 2) & 1);
    const int di    = (wq << 5) + (tb << 1) + piece;
    e1q[row * 128 + di] = (unsigned)pa;
    e2q[row * 128 + di] = (unsigned)pb;

    float s1 = a.x*a.x + a.y*a.y + a.z*a.z + a.w*a.w;
    float s2 = b.x*b.x + b.y*b.y + b.z*b.z + b.w*b.w;
    float dx = a.x-b.x, dy = a.y-b.y, dz = a.z-b.z, dw = a.w-b.w;
    float sp = dx*dx + dy*dy + dz*dz + dw*dw;

    #pragma unroll
    for (int o = 32; o; o >>= 1) {
        s1 += __shfl_down(s1, o);
        s2 += __shfl_down(s2, o);
        sp += __shfl_down(sp, o);
    }
    __shared__ float r1[2], r2[2], rp[2];
    if ((t & 63) == 0) { int wv = t >> 6; r1[wv] = s1; r2[wv] = s2; rp[wv] = sp; }
    __syncthreads();
    if (t == 0) {
        n1[row] = r1[0] + r1[1];
        n2[row] = r2[0] + r2[1];
        dpos[row] = sqrtf(rp[0] + rp[1]);
    }
}

// ---- flat tile decode: tau in [0,2080) -> (flavor, bi, bj) ----
__device__ __forceinline__ void decode_tile(int tau, int& fl, int& bi, int& bj) {
    if (tau < 1024) { fl = 0; bi = tau >> 5; bj = tau & 31; }
    else {
        int b = tau - 1024; fl = 1;
        if (b >= 528) { b -= 528; fl = 2; }
        int r = 0;
        while (b >= 32 - r) { b -= 32 - r; ++r; }
        bi = r; bj = r + b;
    }
}

// =====================================================================
// main: R17 body (identical codegen: (256,3), VGPR 72, LDS 35.3KB, no
// spill) on a 3-BLOCKS/CU one-round grid: 768 blocks, all resident at
// t=0 -> 3 independent barrier domains per CU so one block's
// stage->barrier drain overlaps the other two blocks' MFMA/VALU.
// Per tile: 4 K-steps BK=128 (stage -> sync -> 64 MFMA -> sync), next
// tile's step-0 stage issues before the epilogue.
// grid: 768 blocks x 256 threads; flat tile list 544x3 + 224x2 tiles.
// =====================================================================
__global__ __launch_bounds__(256, 3) void triplet_main(
    const unsigned char* __restrict__ e1q, const unsigned char* __restrict__ e2q,
    const float* __restrict__ n1, const float* __restrict__ n2,
    const float* __restrict__ dpos,
    float* __restrict__ total, unsigned* __restrict__ count)
{
    __shared__ char buf[32768];        // A tile [0,16K) | B tile [16K,32K)
    __shared__ float scRN[128], scRD[128], scCN[128], scCD[128];
    __shared__ float lt[4];
    __shared__ unsigned lc[4];

    const int g    = blockIdx.x;
    int       tau  = (2080 * g) / 768;
    const int tend = (2080 * (g + 1)) / 768;

    const int tid  = threadIdx.x;
    const int w    = tid >> 6;
    const int lane = tid & 63;
    const int l15  = lane & 15;
    const int l4   = lane >> 4;
    const int wr   = w >> 1;      // 0..1
    const int wc   = w & 1;       // 0..1

    // ---- i-relative staging offsets (fp8 row = 512B; window = 128B) ----
    long srcRel[4];
    #pragma unroll
    for (int c = 0; c < 4; ++c) {
        const int chA = tid + (c << 8);              // 0..1023
        const int rA  = chA >> 3;                    // 0..127
        srcRel[c] = (long)rA * 512 + (((chA & 7) << 4) ^ ((rA & 7) << 4));
    }
    const int ldst = w << 10;                        // wave-uniform dest part

#define STAGE(T, XB, YB) do {                                                \
    const long kb_ = (long)(T) << 7;                                         \
    _Pragma("unroll")                                                        \
    for (int c = 0; c < 4; ++c) {                                            \
        gload16((XB) + srcRel[c] + kb_, buf + (c << 12) + ldst);             \
        gload16((YB) + srcRel[c] + kb_, buf + 16384 + (c << 12) + ldst);     \
    }                                                                        \
} while (0)

    // ---- zero-conflict swizzled b128 read bases; khalf = ^64 ----
    const int slot = (l4 << 4) ^ ((l15 & 7) << 4);
    const int aB = ((wr << 6) + l15) * 128 + slot;
    const int bB = 16384 + ((wc << 6) + l15) * 128 + slot;

    fv4 acc[4][4];

#define EPI(EMITCOL, NEEDNEQ) do {                                           \
    float cN_[4], cM_[4];                                                    \
    _Pragma("unroll")                                                        \
    for (int n = 0; n < 4; ++n) {                                            \
        const int cl = (wc << 6) + (n << 4) + l15;                           \
        cN_[n] = scCN[cl]; cM_[n] = scCD[cl] + MARGIN_F;                     \
    }                                                                        \
    _Pragma("unroll")                                                        \
    for (int m = 0; m < 4; ++m) {                                            \
        _Pragma("unroll")                                                    \
        for (int rr = 0; rr < 4; ++rr) {                                     \
            const int rl = (wr << 6) + (m << 4) + (l4 << 2) + rr;            \
            const float rN = scRN[rl];                                       \
            const float rM = scRD[rl] + MARGIN_F;                            \
            _Pragma("unroll")                                                \
            for (int n = 0; n < 4; ++n) {                                    \
                const float D = fmaxf(fmaf(-2.0f, acc[m][n][rr],             \
                                           rN + cN_[n]), 0.0f);              \
                const float s = __builtin_amdgcn_sqrtf(D);                   \
                bool neq = true;                                             \
                if (NEEDNEQ) neq = (rl != ((wc << 6) + (n << 4) + l15));     \
                const float t1 = rM - s;                                     \
                const bool c1 = (t1 < MARGIN_F) && neq;                      \
                lcnt += c1;                                                  \
                ltot += c1 ? fmaxf(t1, 0.0f) : 0.0f;                         \
                if (EMITCOL) {                                               \
                    const float t2 = cM_[n] - s;                             \
                    const bool c2 = (t2 < MARGIN_F) && neq;                  \
                    lcnt += c2;                                              \
                    ltot += c2 ? fmaxf(t2, 0.0f) : 0.0f;                     \
                }                                                            \
            }                                                                \
        }                                                                    \
    }                                                                        \
} while (0)

    // ---- decode + pointers for the first tile ----
    int fl, bi, bj;
    decode_tile(tau, fl, bi, bj);
    int i0 = bi << 7, j0 = bj << 7;
    const char* XB = (const char*)((fl == 2) ? e2q : e1q) + (long)i0 * 512;
    const char* YB = (const char*)((fl == 1) ? e1q : e2q) + (long)j0 * 512;
    const float* nRp = (fl == 2) ? n2 : n1;
    const float* nCp = (fl == 1) ? n1 : n2;

    // ---- prologue: scalars + first stage ----
    if (tid < 128)      { scRN[tid] = nRp[i0 + tid]; scRD[tid] = dpos[i0 + tid]; }
    else { const int t2 = tid - 128; scCN[t2] = nCp[j0 + t2]; scCD[t2] = dpos[j0 + t2]; }
    STAGE(0, XB, YB);

    float    ltot = 0.0f;
    unsigned lcnt = 0;

    for (;;) {
        const bool hasNext = (tau + 1 < tend);
        int nfl = 0, nbi = 0, nbj = 0, ni0 = 0, nj0 = 0;
        const char *nXB = XB, *nYB = YB;
        const float *nnR = nRp, *nnC = nCp;
        if (hasNext) {
            decode_tile(tau + 1, nfl, nbi, nbj);
            ni0 = nbi << 7; nj0 = nbj << 7;
            nXB = (const char*)((nfl == 2) ? e2q : e1q) + (long)ni0 * 512;
            nYB = (const char*)((nfl == 1) ? e1q : e2q) + (long)nj0 * 512;
            nnR = (nfl == 2) ? n2 : n1;
            nnC = (nfl == 1) ? n1 : n2;
        }

        #pragma unroll
        for (int m = 0; m < 4; ++m)
            #pragma unroll
            for (int n = 0; n < 4; ++n) acc[m][n] = (fv4)0.0f;

        // ---- K-loop: sync(stage landed) -> compute -> sync -> stage next --
        for (int t = 0; t < 4; ++t) {
            __syncthreads();
            #pragma unroll
            for (int h = 0; h < 2; ++h) {
                const int H = h << 6;
                lv2 a_[4], b_[4];
                #pragma unroll
                for (int m = 0; m < 4; ++m)
                    a_[m] = *(const lv2*)(buf + ((aB + m * 2048) ^ H));
                #pragma unroll
                for (int n = 0; n < 4; ++n)
                    b_[n] = *(const lv2*)(buf + ((bB + n * 2048) ^ H));
                #pragma unroll
                for (int m = 0; m < 4; ++m)
                    #pragma unroll
                    for (int n = 0; n < 4; ++n) {
                        acc[m][n] = __builtin_amdgcn_mfma_f32_16x16x32_fp8_fp8(
                            a_[m][0], b_[n][0], acc[m][n], 0, 0, 0);
                        acc[m][n] = __builtin_amdgcn_mfma_f32_16x16x32_fp8_fp8(
                            a_[m][1], b_[n][1], acc[m][n], 0, 0, 0);
                    }
            }
            __syncthreads();
            if (t < 3)      STAGE(t + 1, XB, YB);
            else if (hasNext) STAGE(0, nXB, nYB);   // hides under epilogue
        }

        // ---- lean specialized epilogue for this tile ----
        if (i0 != j0)      EPI(true, false);   // hot path
        else if (fl == 0)  EPI(true, true);    // G12 diag tiles
        else               EPI(false, true);   // G11/G22 diag tiles

        if (!hasNext) break;

        // ---- swap in next tile's scalars (behind barrier) ----
        __syncthreads();                 // epilogue scalar reads complete
        if (tid < 128)      { scRN[tid] = nnR[ni0 + tid]; scRD[tid] = dpos[ni0 + tid]; }
        else { const int t2 = tid - 128; scCN[t2] = nnC[nj0 + t2]; scCD[t2] = dpos[nj0 + t2]; }
        // next K-loop's first __syncthreads publishes these writes
        fl = nfl; i0 = ni0; j0 = nj0; XB = nXB; YB = nYB; nRp = nnR; nCp = nnC;
        ++tau;
    }
#undef STAGE
#undef EPI

    // ---- block reduction: wave shuffle -> LDS -> one atomic pair ----
    #pragma unroll
    for (int o = 32; o; o >>= 1) {
        ltot += __shfl_down(ltot, o);
        lcnt += __shfl_down(lcnt, o);
    }
    __syncthreads();
    if (lane == 0) { lt[w] = ltot; lc[w] = lcnt; }
    __syncthreads();
    if (tid == 0) {
        float T = 0.0f; unsigned C = 0;
        #pragma unroll
        for (int x = 0; x < 4; ++x) { T += lt[x]; C += lc[x]; }
        atomicAdd(total, T);
        atomicAdd(count, C);
    }
}

__global__ void finalize_kernel(const float* __restrict__ total,
                                const unsigned* __restrict__ count,
                                float* __restrict__ out)
{
    out[0] = total[0] / fmaxf((float)count[0], 1.0f);
}

// =====================================================================
// Workspace layout (~4.5 MB):
//   [0,8)        : total (f32), count (u32)
//   [1024, ...)  : n1[4096], n2[4096], dpos[4096]  (f32)
//   [131072, ..) : e1q 4096x512 fp8 (2MB), then e2q (2MB)
// =====================================================================
extern "C" void kernel_launch(void* const* d_in, const int* in_sizes, int n_in,
                              void* d_out, int out_size, void* d_ws, size_t ws_size,
                              hipStream_t stream) {
    const float* e1 = (const float*)d_in[0];
    const float* e2 = (const float*)d_in[1];
    char* ws = (char*)d_ws;

    float*    total = (float*)ws;
    unsigned* count = (unsigned*)(ws + 4);
    float* n1   = (float*)(ws + 1024);
    float* n2   = n1 + 4096;
    float* dpos = n2 + 4096;
    unsigned* e1q = (unsigned*)(ws + (1 << 17));
    unsigned* e2q = e1q + (size_t)4096 * 128;

    hipMemsetAsync(ws, 0, 64, stream);
    prep_kernel<<<4096, 128, 0, stream>>>(e1, e2, e1q, e2q, n1, n2, dpos);
    triplet_main<<<768, 256, 0, stream>>>((const unsigned char*)e1q,
                                          (const unsigned char*)e2q,
                                          n1, n2, dpos, total, count);
    finalize_kernel<<<1, 1, 0, stream>>>(total, count, (float*)d_out);
}